// Round 13
// baseline (81.571 us; speedup 1.0000x reference)
//
#include <hip/hip_runtime.h>
#include <math.h>

// Problem constants (match reference)
#define B_ 2
#define T_ 2048
#define M_ 768
#define R_ 64
#define S_ 16
#define MS_ (M_ * S_)
#define NC 128
#define CL 16              // T_ / NC
#define LOG2E 1.4426950408889634f
#define LOG2_EPS (-33.219280948873623f)   // log2(1e-10)

// --------------------------------------------------------------------------
// Kernel 1 (round-5 proven): dt = clip(softplus(delta . dt_w^T + b)).
// Tiled 64x64, K=64, LDS transpose staging, coalesced everywhere.
// --------------------------------------------------------------------------
__global__ __launch_bounds__(256) void dt_kernel(
    const float* __restrict__ delta,   // [B*T][R]
    const float* __restrict__ dt_w,    // [M][R]
    const float* __restrict__ dt_b,    // [M]
    float* __restrict__ dt_out)        // [B*T][M]
{
  __shared__ float ds_d[R_][68];
  __shared__ float ds_w[R_][68];
  const int tid = threadIdx.x;
  const int m0  = blockIdx.x * 64;
  const int bt0 = blockIdx.y * 64;

  #pragma unroll
  for (int k = 0; k < 4; ++k) {
    int idx = tid + k * 256;
    int rq = idx & 15;
    int x  = idx >> 4;
    float4 dv = *reinterpret_cast<const float4*>(&delta[(size_t)(bt0 + x) * R_ + rq * 4]);
    ds_d[rq * 4 + 0][x] = dv.x; ds_d[rq * 4 + 1][x] = dv.y;
    ds_d[rq * 4 + 2][x] = dv.z; ds_d[rq * 4 + 3][x] = dv.w;
    float4 wv = *reinterpret_cast<const float4*>(&dt_w[(size_t)(m0 + x) * R_ + rq * 4]);
    ds_w[rq * 4 + 0][x] = wv.x; ds_w[rq * 4 + 1][x] = wv.y;
    ds_w[rq * 4 + 2][x] = wv.z; ds_w[rq * 4 + 3][x] = wv.w;
  }
  __syncthreads();

  const int mq = tid & 15, tq = tid >> 4;
  const int ml = mq * 4, tl = tq * 4;
  float acc[4][4] = {};
  #pragma unroll 4
  for (int r = 0; r < R_; ++r) {
    float4 dv = *reinterpret_cast<const float4*>(&ds_d[r][tl]);
    float4 wv = *reinterpret_cast<const float4*>(&ds_w[r][ml]);
    float d[4] = {dv.x, dv.y, dv.z, dv.w};
    float w[4] = {wv.x, wv.y, wv.z, wv.w};
    #pragma unroll
    for (int i = 0; i < 4; ++i)
      #pragma unroll
      for (int j = 0; j < 4; ++j)
        acc[i][j] = fmaf(d[i], w[j], acc[i][j]);
  }

  float4 bb = *reinterpret_cast<const float4*>(&dt_b[m0 + ml]);
  float bv[4] = {bb.x, bb.y, bb.z, bb.w};
  #pragma unroll
  for (int i = 0; i < 4; ++i) {
    float4 o;
    float* op = &o.x;
    #pragma unroll
    for (int j = 0; j < 4; ++j) {
      float x = acc[i][j] + bv[j];
      float sp = (x > 20.f) ? x : __logf(1.f + __expf(x));
      op[j] = fminf(fmaxf(sp, 1e-6f), 10.f);
    }
    *reinterpret_cast<float4*>(&dt_out[(size_t)(bt0 + tl + i) * M_ + m0 + ml]) = o;
  }
}

// --------------------------------------------------------------------------
// Kernel 2 (bc v6, proven): register-cached W slices, fold+pack butterfly.
// 0 LDS, 512 thr, launch_bounds(512,4).
// --------------------------------------------------------------------------
__global__ __launch_bounds__(512, 4) void bc_kernel(
    const float* __restrict__ u,     // [B*T][M]
    const float* __restrict__ B_w,   // [S][M]
    const float* __restrict__ C_w,   // [S][M]
    float* __restrict__ Bm,          // [B*T][S]
    float* __restrict__ Cm)          // [B*T][S]
{
  const int wave = threadIdx.x >> 6, lane = threadIdx.x & 63;
  const int bt0 = blockIdx.x * 8;

  float4 w[4][3];
  #pragma unroll
  for (int s = 0; s < 4; ++s) {
    const int s_g = wave * 4 + s;
    const float* wr = (s_g < 16) ? &B_w[(size_t)s_g * M_] : &C_w[(size_t)(s_g - 16) * M_];
    const float4* w4 = reinterpret_cast<const float4*>(wr);
    w[s][0] = w4[lane]; w[s][1] = w4[64 + lane]; w[s][2] = w4[128 + lane];
  }

  float acc[32];
  #pragma unroll
  for (int r = 0; r < 8; ++r) {
    const float4* ur = reinterpret_cast<const float4*>(&u[(size_t)(bt0 + r) * M_]);
    const float4 a0 = ur[lane], a1 = ur[64 + lane], a2 = ur[128 + lane];
    #pragma unroll
    for (int s = 0; s < 4; ++s) {
      float t = 0.f;
      t = fmaf(a0.x, w[s][0].x, t); t = fmaf(a0.y, w[s][0].y, t);
      t = fmaf(a0.z, w[s][0].z, t); t = fmaf(a0.w, w[s][0].w, t);
      t = fmaf(a1.x, w[s][1].x, t); t = fmaf(a1.y, w[s][1].y, t);
      t = fmaf(a1.z, w[s][1].z, t); t = fmaf(a1.w, w[s][1].w, t);
      t = fmaf(a2.x, w[s][2].x, t); t = fmaf(a2.y, w[s][2].y, t);
      t = fmaf(a2.z, w[s][2].z, t); t = fmaf(a2.w, w[s][2].w, t);
      acc[r * 4 + s] = t;
    }
  }

  #pragma unroll
  for (int j = 0; j < 32; ++j) acc[j] += __shfl_xor(acc[j], 32);
  int cnt = 32;
  #pragma unroll
  for (int mask = 16; mask >= 1; mask >>= 1) {
    cnt >>= 1;
    const bool up = (lane & mask) != 0;
    #pragma unroll
    for (int j = 0; j < cnt; ++j) {
      float give = up ? acc[j] : acc[j + cnt];
      float keep = up ? acc[j + cnt] : acc[j];
      acc[j] = keep + __shfl_xor(give, mask);
    }
  }

  if (lane < 32) {
    const int r = lane >> 2, s_l = lane & 3;
    const int s_g = wave * 4 + s_l;
    const int bt = bt0 + r;
    if (s_g < 16) Bm[(size_t)bt * S_ + s_g] = acc[0];
    else          Cm[(size_t)bt * S_ + (s_g - 16)] = acc[0];
  }
}

// --------------------------------------------------------------------------
// Kernels 3 & 5 (scan v8, the ONLY change vs the 70.3 µs round-5 config):
// R5 geometry (NC=128, CL=16, 3072 single-shot 128-thr blocks, LDS-staged
// dt/u/bm/cm) with a batched-exp inner loop: per 4-step group all 32
// independent exp2 values are computed first (trans-pipe ILP), then the
// pure-FMA h-updates. exp2-domain decay (numerics verified r8/r12).
// Summaries [B][NC][S][M]; Aprod doubles as carry buffer after kernel 4.
// --------------------------------------------------------------------------
template <int PHASE>
__global__ __launch_bounds__(128) void scan_v8(
    const float* __restrict__ dt_ws,   // [B*T][M]
    const float* __restrict__ u,       // [B*T][M]
    const float* __restrict__ Bm,      // [B*T][S]
    const float* __restrict__ Cm,      // [B*T][S]
    const float* __restrict__ A_log,   // [S][M]
    const float* __restrict__ D,       // [M]
    float* __restrict__ Aprod,         // [B][NC][S][M]; carry after kernel 4
    float* __restrict__ Hend,          // [B][NC][S][M]
    float* __restrict__ out)           // [B*T][M]
{
  __shared__ float dt_lds[CL][64];     // 4 KB
  __shared__ float u_lds[CL][64];      // 4 KB
  __shared__ float bm_lds[CL * S_];    // 1 KB
  __shared__ float cm_lds[CL * S_];    // 1 KB

  const int tid = threadIdx.x;
  const int mt = blockIdx.x;               // 0..11
  const int c  = blockIdx.y;               // 0..127
  const int b  = blockIdx.z;
  const int m0 = mt * 64;
  const size_t row0 = (size_t)b * T_ + (size_t)c * CL;

  // ---- stage dt/u ([16][64], coalesced float4) + bm/cm ----
  #pragma unroll
  for (int p = 0; p < 2; ++p) {
    const int i4 = tid + p * 128;
    const int t = i4 >> 4, m4 = (i4 & 15) * 4;
    *reinterpret_cast<float4*>(&dt_lds[t][m4]) =
        *reinterpret_cast<const float4*>(&dt_ws[(row0 + t) * M_ + m0 + m4]);
    *reinterpret_cast<float4*>(&u_lds[t][m4]) =
        *reinterpret_cast<const float4*>(&u[(row0 + t) * M_ + m0 + m4]);
  }
  {
    const size_t bcb = row0 * S_;
    bm_lds[tid]       = Bm[bcb + tid];
    bm_lds[tid + 128] = Bm[bcb + tid + 128];
    if constexpr (PHASE == 3) {
      cm_lds[tid]       = Cm[bcb + tid];
      cm_lds[tid + 128] = Cm[bcb + tid + 128];
    }
  }

  const int lane = tid & 63, wv = tid >> 6;
  const int m_l = wv * 32 + (lane & 31);   // 0..63
  const int sh = lane >> 5, s0 = sh * 8;
  const int m = m0 + m_l;

  float A2[8];
  #pragma unroll
  for (int s = 0; s < 8; ++s) {
    const float a = -__expf(A_log[(size_t)(s0 + s) * M_ + m]);
    A2[s] = fminf(fmaxf(a, -10.f), -1e-6f) * LOG2E;
  }

  float h[8], Sla[8], Dm = 0.f;
  const size_t smb = (((size_t)b * NC + c) * S_ + s0) * M_ + m;
  if constexpr (PHASE == 1) {
    #pragma unroll
    for (int s = 0; s < 8; ++s) { h[s] = 0.f; Sla[s] = 0.f; }
  } else {
    #pragma unroll
    for (int s = 0; s < 8; ++s) h[s] = Aprod[smb + (size_t)s * M_];  // carry
    Dm = D[m];
  }
  __syncthreads();

  // ---- scan: groups of 4 t-steps; batch the 32 exps, then FMA block ----
  #pragma unroll
  for (int tg = 0; tg < CL; tg += 4) {
    float e[4][8], dus[4];
    #pragma unroll
    for (int k = 0; k < 4; ++k) {
      const float dtv = dt_lds[tg + k][m_l];
      dus[k] = dtv * u_lds[tg + k][m_l];
      #pragma unroll
      for (int s = 0; s < 8; ++s) {
        const float la = fmaxf(dtv * A2[s], LOG2_EPS);
        e[k][s] = exp2f(la);
        if constexpr (PHASE == 1) Sla[s] += la;
      }
    }
    #pragma unroll
    for (int k = 0; k < 4; ++k) {
      const int t = tg + k;
      const float4 bv0 = *reinterpret_cast<const float4*>(&bm_lds[t * S_ + s0]);
      const float4 bv1 = *reinterpret_cast<const float4*>(&bm_lds[t * S_ + s0 + 4]);
      const float bmv[8] = {bv0.x, bv0.y, bv0.z, bv0.w, bv1.x, bv1.y, bv1.z, bv1.w};
      float cmv[8];
      if constexpr (PHASE == 3) {
        const float4 cv0 = *reinterpret_cast<const float4*>(&cm_lds[t * S_ + s0]);
        const float4 cv1 = *reinterpret_cast<const float4*>(&cm_lds[t * S_ + s0 + 4]);
        cmv[0] = cv0.x; cmv[1] = cv0.y; cmv[2] = cv0.z; cmv[3] = cv0.w;
        cmv[4] = cv1.x; cmv[5] = cv1.y; cmv[6] = cv1.z; cmv[7] = cv1.w;
      }
      float y = 0.f;
      #pragma unroll
      for (int s = 0; s < 8; ++s) {
        h[s] = fmaf(e[k][s], h[s], dus[k] * bmv[s]);
        if constexpr (PHASE == 3) y = fmaf(h[s], cmv[s], y);
      }
      if constexpr (PHASE == 3) {
        y += __shfl_xor(y, 32);
        if (sh == 0) {
          const float o = y + u_lds[t][m_l] * Dm;
          out[(row0 + t) * M_ + m] = fminf(fmaxf(o, -1e4f), 1e4f);
        }
      }
    }
  }

  if constexpr (PHASE == 1) {
    #pragma unroll
    for (int s = 0; s < 8; ++s) {
      Aprod[smb + (size_t)s * M_] = exp2f(Sla[s]);   // chunk decay product
      Hend[smb + (size_t)s * M_]  = h[s];
    }
  }
}

// --------------------------------------------------------------------------
// Kernel 4: chunk-carry combine, in place (NC=128): Aprod[c] read (decay
// product) then overwritten with the carry entering chunk c.
// --------------------------------------------------------------------------
__global__ __launch_bounds__(256) void carry_kernel(
    float* __restrict__ Aprod, const float* __restrict__ Hend)
{
  const int idx = blockIdx.x * 256 + threadIdx.x;  // over B*S*M
  const int b = idx / MS_;
  const int sm = idx - b * MS_;
  float h = 0.f;
  #pragma unroll 16
  for (int c = 0; c < NC; ++c) {
    const size_t o = ((size_t)b * NC + c) * MS_ + sm;
    const float a  = Aprod[o];
    const float he = Hend[o];
    Aprod[o] = h;                 // carry into chunk c
    h = fmaf(a, h, he);
  }
}

// --------------------------------------------------------------------------
extern "C" void kernel_launch(void* const* d_in, const int* in_sizes, int n_in,
                              void* d_out, int out_size, void* d_ws, size_t ws_size,
                              hipStream_t stream)
{
  const float* u     = (const float*)d_in[0];
  const float* delta = (const float*)d_in[1];
  const float* dt_w  = (const float*)d_in[2];
  const float* dt_b  = (const float*)d_in[3];
  const float* A_log = (const float*)d_in[4];
  const float* B_w   = (const float*)d_in[5];
  const float* C_w   = (const float*)d_in[6];
  const float* D     = (const float*)d_in[7];
  float* out = (float*)d_out;
  float* ws  = (float*)d_ws;

  const size_t fl_dt = (size_t)B_ * T_ * M_;   // 3,145,728
  const size_t fl_bc = (size_t)B_ * T_ * S_;   // 65,536
  const size_t fl_sm = (size_t)B_ * NC * MS_;  // 3,145,728

  float* dt_ws = ws;
  float* Bm    = dt_ws + fl_dt;
  float* Cm    = Bm + fl_bc;
  float* Aprod = Cm + fl_bc;         // later holds carries
  float* Hend  = Aprod + fl_sm;      // total ~38 MB

  dt_kernel<<<dim3(M_ / 64, (B_ * T_) / 64), 256, 0, stream>>>(delta, dt_w, dt_b, dt_ws);
  bc_kernel<<<dim3((B_ * T_) / 8), 512, 0, stream>>>(u, B_w, C_w, Bm, Cm);
  scan_v8<1><<<dim3(M_ / 64, NC, B_), 128, 0, stream>>>(
      dt_ws, u, Bm, Cm, A_log, D, Aprod, Hend, nullptr);
  carry_kernel<<<dim3((B_ * MS_) / 256), 256, 0, stream>>>(Aprod, Hend);
  scan_v8<3><<<dim3(M_ / 64, NC, B_), 128, 0, stream>>>(
      dt_ws, u, Bm, Cm, A_log, D, Aprod, Hend, out);
}